// Round 9
// baseline (6026.863 us; speedup 1.0000x reference)
//
#include <hip/hip_runtime.h>
#include <hip/hip_fp16.h>

typedef _Float16 h2 __attribute__((ext_vector_type(2)));
typedef _Float16 h8 __attribute__((ext_vector_type(8)));
typedef float f4 __attribute__((ext_vector_type(4)));
typedef unsigned int uv16 __attribute__((ext_vector_type(16)));

static constexpr int TT = 2048;
static constexpr int BB = 64;
static constexpr int II = 256;
static constexpr int HH = 256;
static constexpr int G3 = 768;   // 3*H

static __device__ __forceinline__ unsigned int pk2(float a, float b) {
    return __builtin_bit_cast(unsigned int, __builtin_amdgcn_cvt_pkrtz(a, b));
}
static __device__ __forceinline__ float fdot2u(unsigned int w, unsigned int h, float acc) {
    return __builtin_amdgcn_fdot2(__builtin_bit_cast(h2, w), __builtin_bit_cast(h2, h), acc, false);
}
// 16 fdot2 of one uv16 weight block against 16 packed h uints
static __device__ __forceinline__ float dot16(uv16 W, uint4 A, uint4 B, uint4 C, uint4 D, float s) {
    float a0 = 0.f, a1 = 0.f, a2 = 0.f, a3 = 0.f;
    a0 = fdot2u(W[0],  A.x, a0); a1 = fdot2u(W[1],  A.y, a1);
    a2 = fdot2u(W[2],  A.z, a2); a3 = fdot2u(W[3],  A.w, a3);
    a0 = fdot2u(W[4],  B.x, a0); a1 = fdot2u(W[5],  B.y, a1);
    a2 = fdot2u(W[6],  B.z, a2); a3 = fdot2u(W[7],  B.w, a3);
    a0 = fdot2u(W[8],  C.x, a0); a1 = fdot2u(W[9],  C.y, a1);
    a2 = fdot2u(W[10], C.z, a2); a3 = fdot2u(W[11], C.w, a3);
    a0 = fdot2u(W[12], D.x, a0); a1 = fdot2u(W[13], D.y, a1);
    a2 = fdot2u(W[14], D.z, a2); a3 = fdot2u(W[15], D.w, a3);
    return s + ((a0 + a1) + (a2 + a3));
}

// ---------------------------------------------------------------------------
// Kernel 0: cast W_ih fp32 -> fp16 (tiny, one-time)
// ---------------------------------------------------------------------------
__global__ void cast_wih(const float* __restrict__ w, _Float16* __restrict__ o, int n) {
    int i = blockIdx.x * blockDim.x + threadIdx.x;
    if (i < n) o[i] = (_Float16)w[i];
}

// ---------------------------------------------------------------------------
// Kernel 1: gi = x @ W_ih^T + b_ih, stored fp16 [B*T][768]
// Per-wave 64x64 C tile, K=256, no LDS. MFMA f32_16x16x32_f16.
// ---------------------------------------------------------------------------
__global__ void gi_gemm(const float* __restrict__ x, const _Float16* __restrict__ wih,
                        const float* __restrict__ bih, _Float16* __restrict__ gi) {
    const int lane = threadIdx.x & 63;
    const int wid  = threadIdx.x >> 6;
    const int gt   = blockIdx.x * 4 + wid;       // wave-tile id, n fastest
    const int nt   = gt % 12;
    const int mt   = gt / 12;
    const int m0   = mt * 64;
    const int n0   = nt * 64;
    const int lr   = lane & 15;
    const int kg   = (lane >> 4) * 8;

    f4 acc[4][4] = {};

    #pragma unroll
    for (int kk = 0; kk < 256; kk += 32) {
        h8 af[4];
        h8 bf[4];
        #pragma unroll
        for (int m = 0; m < 4; ++m) {
            const float* ap = x + (size_t)(m0 + m * 16 + lr) * 256 + kk + kg;
            f4 lo = *(const f4*)ap;
            f4 hi = *(const f4*)(ap + 4);
            uint4 uu;
            uu.x = pk2(lo.x, lo.y);
            uu.y = pk2(lo.z, lo.w);
            uu.z = pk2(hi.x, hi.y);
            uu.w = pk2(hi.z, hi.w);
            af[m] = __builtin_bit_cast(h8, uu);
        }
        #pragma unroll
        for (int n = 0; n < 4; ++n) {
            bf[n] = *(const h8*)(wih + (size_t)(n0 + n * 16 + lr) * 256 + kk + kg);
        }
        #pragma unroll
        for (int m = 0; m < 4; ++m) {
            #pragma unroll
            for (int n = 0; n < 4; ++n) {
                acc[m][n] = __builtin_amdgcn_mfma_f32_16x16x32_f16(af[m], bf[n], acc[m][n], 0, 0, 0);
            }
        }
    }

    const int rg = (lane >> 4) * 4;
    #pragma unroll
    for (int n = 0; n < 4; ++n) {
        const int col = n0 + n * 16 + lr;
        const float bv = bih[col];
        #pragma unroll
        for (int m = 0; m < 4; ++m) {
            #pragma unroll
            for (int r = 0; r < 4; ++r) {
                const int row = m0 + m * 16 + rg + r;
                gi[(size_t)row * G3 + col] = (_Float16)(acc[m][n][r] + bv);
            }
        }
    }
}

// ---------------------------------------------------------------------------
// Kernel 2: sequential GRU scan. One workgroup per batch element.
// 256 threads = 4 waves = 1 wave/SIMD -> 512-VGPR budget (arch 256 +
// AGPR overflow; CDNA VALU reads AGPRs directly). Thread tid owns ALL
// THREE gate rows {tid, 256+tid, 512+tid} x full K=256: 3 x 8 uv16 =
// 384 packed-f16x2 weight regs. Consequences: no gh exchange, no
// swizzle reduce, ONE barrier/step (double-buffered h), and h reads
// are same-address broadcasts (conflict-free).
// n-gate bias is r-gated: n = tanh(i_n + r*(dot_n + b_hn)).
// ---------------------------------------------------------------------------
__global__ __launch_bounds__(256, 1)
void gru_scan(
        const _Float16* __restrict__ gi, const float* __restrict__ whh,
        const float* __restrict__ bhh, float* __restrict__ out) {
    __shared__ alignas(16) unsigned int hpk[2][128];  // h as packed f16x2, dbuf

    const int b   = blockIdx.x;
    const int tid = threadIdx.x;

    // Load 3 weight rows (full K) into registers.
    uv16 W0[8], W1[8], W2[8];
    #pragma unroll
    for (int i = 0; i < 8; ++i) {
        const f4* p0 = (const f4*)(whh + (size_t)tid * 256 + i * 32);
        const f4* p1 = (const f4*)(whh + (size_t)(256 + tid) * 256 + i * 32);
        const f4* p2 = (const f4*)(whh + (size_t)(512 + tid) * 256 + i * 32);
        uv16 a, c, d;
        #pragma unroll
        for (int k = 0; k < 8; ++k) {
            f4 v0 = p0[k], v1 = p1[k], v2 = p2[k];
            a[2 * k] = pk2(v0.x, v0.y); a[2 * k + 1] = pk2(v0.z, v0.w);
            c[2 * k] = pk2(v1.x, v1.y); c[2 * k + 1] = pk2(v1.z, v1.w);
            d[2 * k] = pk2(v2.x, v2.y); d[2 * k + 1] = pk2(v2.z, v2.w);
        }
        W0[i] = a; W1[i] = c; W2[i] = d;
    }

    const float b_r = bhh[tid];
    const float b_z = bhh[256 + tid];
    const float b_n = bhh[512 + tid];

    if (tid < 128) { hpk[0][tid] = 0u; hpk[1][tid] = 0u; }

    // 2-deep gi prefetch
    const _Float16* gb = gi + (size_t)b * TT * G3;
    float c_r = (float)gb[tid];
    float c_z = (float)gb[256 + tid];
    float c_n = (float)gb[512 + tid];
    float n_r = (float)gb[G3 + tid];
    float n_z = (float)gb[G3 + 256 + tid];
    float n_n = (float)gb[G3 + 512 + tid];
    float hcur = 0.f;
    __syncthreads();

    for (int t = 0; t < TT; ++t) {
        // issue loads for step t+2
        float p_r = 0.f, p_z = 0.f, p_n = 0.f;
        if (t + 2 < TT) {
            const _Float16* g2 = gb + (size_t)(t + 2) * G3;
            p_r = (float)g2[tid];
            p_z = (float)g2[256 + tid];
            p_n = (float)g2[512 + tid];
        }

        // 3 full-row dots, streaming h in 16-uint blocks (broadcast reads)
        const uint4* hb = (const uint4*)hpk[t & 1];
        float s0 = 0.f, s1 = 0.f, s2 = 0.f;
        #pragma unroll
        for (int i = 0; i < 8; ++i) {
            const uint4 A = hb[4 * i], B = hb[4 * i + 1], C = hb[4 * i + 2], D = hb[4 * i + 3];
            s0 = dot16(W0[i], A, B, C, D, s0);
            s1 = dot16(W1[i], A, B, C, D, s1);
            s2 = dot16(W2[i], A, B, C, D, s2);
        }

        // gate math (this thread owns h element tid)
        const float xr = c_r + b_r + s0;
        const float xz = c_z + b_z + s1;
        const float r = __builtin_amdgcn_rcpf(1.f + __expf(-xr));
        const float z = __builtin_amdgcn_rcpf(1.f + __expf(-xz));
        // b_hn must be r-gated: n = tanh(i_n + r*(dot_n + b_hn))
        const float xn = c_n + r * (s2 + b_n);
        const float th = 1.f - 2.f * __builtin_amdgcn_rcpf(__expf(2.f * xn) + 1.f);
        hcur = (1.f - z) * th + z * hcur;

        ((_Float16*)hpk[(t + 1) & 1])[tid] = (_Float16)hcur;
        c_r = n_r; c_z = n_z; c_n = n_n;
        n_r = p_r; n_z = p_z; n_n = p_n;
        __syncthreads();
    }

    out[(size_t)b * HH + tid] = hcur;
}

// ---------------------------------------------------------------------------
extern "C" void kernel_launch(void* const* d_in, const int* in_sizes, int n_in,
                              void* d_out, int out_size, void* d_ws, size_t ws_size,
                              hipStream_t stream) {
    const float* x   = (const float*)d_in[0];
    const float* wih = (const float*)d_in[1];
    const float* whh = (const float*)d_in[2];
    const float* bih = (const float*)d_in[3];
    const float* bhh = (const float*)d_in[4];
    float* out = (float*)d_out;

    // workspace: [0, 384KB) W_ih fp16 ; [512KB, 512KB+192MB) gi fp16
    _Float16* wih_h = (_Float16*)d_ws;
    _Float16* gi    = (_Float16*)((char*)d_ws + 512 * 1024);

    cast_wih<<<768, 256, 0, stream>>>(wih, wih_h, G3 * II);
    gi_gemm<<<6144, 256, 0, stream>>>(x, wih_h, bih, gi);
    gru_scan<<<BB, 256, 0, stream>>>(gi, whh, bhh, out);
}

// Round 10
// 5346.125 us; speedup vs baseline: 1.1273x; 1.1273x over previous
//
#include <hip/hip_runtime.h>
#include <hip/hip_fp16.h>

typedef _Float16 h2 __attribute__((ext_vector_type(2)));
typedef _Float16 h8 __attribute__((ext_vector_type(8)));
typedef float f4 __attribute__((ext_vector_type(4)));
typedef unsigned int uv16 __attribute__((ext_vector_type(16)));

static constexpr int TT = 2048;
static constexpr int BB = 64;
static constexpr int II = 256;
static constexpr int HH = 256;
static constexpr int G3 = 768;   // 3*H

static __device__ __forceinline__ unsigned int pk2(float a, float b) {
    return __builtin_bit_cast(unsigned int, __builtin_amdgcn_cvt_pkrtz(a, b));
}
static __device__ __forceinline__ float fdot2u(unsigned int w, unsigned int h, float acc) {
    return __builtin_amdgcn_fdot2(__builtin_bit_cast(h2, w), __builtin_bit_cast(h2, h), acc, false);
}
template <int Q>  // quad Q (0..3) of a uv16 against one h-quad
static __device__ __forceinline__ float dotq16(uv16 W, uint4 hq, float s) {
    s = fdot2u(W[4 * Q + 0], hq.x, s);
    s = fdot2u(W[4 * Q + 1], hq.y, s);
    s = fdot2u(W[4 * Q + 2], hq.z, s);
    s = fdot2u(W[4 * Q + 3], hq.w, s);
    return s;
}
static __device__ __forceinline__ float dotq4(uint4 W, uint4 hq, float s) {
    s = fdot2u(W.x, hq.x, s); s = fdot2u(W.y, hq.y, s);
    s = fdot2u(W.z, hq.z, s); s = fdot2u(W.w, hq.w, s);
    return s;
}

// ---------------------------------------------------------------------------
// Kernel 0: cast W_ih fp32 -> fp16 (tiny, one-time)
// ---------------------------------------------------------------------------
__global__ void cast_wih(const float* __restrict__ w, _Float16* __restrict__ o, int n) {
    int i = blockIdx.x * blockDim.x + threadIdx.x;
    if (i < n) o[i] = (_Float16)w[i];
}

// ---------------------------------------------------------------------------
// Kernel 1: gi = x @ W_ih^T + bias, stored fp16 [B*T][768]
// bias = bih + bhh for the r,z gate columns (purely additive there);
// the n-gate keeps only bih (b_hn is r-gated, applied in the scan).
// Per-wave 64x64 C tile, K=256, no LDS. MFMA f32_16x16x32_f16.
// ---------------------------------------------------------------------------
__global__ void gi_gemm(const float* __restrict__ x, const _Float16* __restrict__ wih,
                        const float* __restrict__ bih, const float* __restrict__ bhh,
                        _Float16* __restrict__ gi) {
    const int lane = threadIdx.x & 63;
    const int wid  = threadIdx.x >> 6;
    const int gt   = blockIdx.x * 4 + wid;       // wave-tile id, n fastest
    const int nt   = gt % 12;
    const int mt   = gt / 12;
    const int m0   = mt * 64;
    const int n0   = nt * 64;
    const int lr   = lane & 15;
    const int kg   = (lane >> 4) * 8;

    f4 acc[4][4] = {};

    #pragma unroll
    for (int kk = 0; kk < 256; kk += 32) {
        h8 af[4];
        h8 bf[4];
        #pragma unroll
        for (int m = 0; m < 4; ++m) {
            const float* ap = x + (size_t)(m0 + m * 16 + lr) * 256 + kk + kg;
            f4 lo = *(const f4*)ap;
            f4 hi = *(const f4*)(ap + 4);
            uint4 uu;
            uu.x = pk2(lo.x, lo.y);
            uu.y = pk2(lo.z, lo.w);
            uu.z = pk2(hi.x, hi.y);
            uu.w = pk2(hi.z, hi.w);
            af[m] = __builtin_bit_cast(h8, uu);
        }
        #pragma unroll
        for (int n = 0; n < 4; ++n) {
            bf[n] = *(const h8*)(wih + (size_t)(n0 + n * 16 + lr) * 256 + kk + kg);
        }
        #pragma unroll
        for (int m = 0; m < 4; ++m) {
            #pragma unroll
            for (int n = 0; n < 4; ++n) {
                acc[m][n] = __builtin_amdgcn_mfma_f32_16x16x32_f16(af[m], bf[n], acc[m][n], 0, 0, 0);
            }
        }
    }

    const int rg = (lane >> 4) * 4;
    #pragma unroll
    for (int n = 0; n < 4; ++n) {
        const int col = n0 + n * 16 + lr;
        const float bv = bih[col] + (col < 512 ? bhh[col] : 0.0f);
        #pragma unroll
        for (int m = 0; m < 4; ++m) {
            #pragma unroll
            for (int r = 0; r < 4; ++r) {
                const int row = m0 + m * 16 + rg + r;
                gi[(size_t)row * G3 + col] = (_Float16)(acc[m][n][r] + bv);
            }
        }
    }
}

// ---------------------------------------------------------------------------
// Kernel 2: sequential GRU scan. One WG (256 thr) per batch element.
// Allocator law (R2..R9): budget = 2048/(2*waves_per_WG) -> only 256-thread
// blocks get 256 VGPRs. W_hh split to fit BOTH budgets:
//   VGPR: row_r (8 uv16 = 128u) + row_z quads 0..24 (6 uv16 + uint4 = 100u)
//   LDS : row_z quads 25..31 (7) + row_n quads 0..31 (32) = 39 uint4/thread
//         = 159744 B, + 1 KB double-buffered h = 160768 B dynamic LDS.
// Thread tid owns h-element tid fully: no cross-lane reduce, 1 barrier/step.
// LDS-W reads: lane-consecutive 16B b128 (conflict-free); h reads broadcast.
// n-gate bias r-gated: n = tanh(i_n + r*(dot_n + b_hn)); r/z biases in gi.
// ---------------------------------------------------------------------------
__global__ __launch_bounds__(256, 1)
void gru_scan(const _Float16* __restrict__ gi, const float* __restrict__ whh,
              const float* __restrict__ bhh, float* __restrict__ out) {
    extern __shared__ char smem[];
    uint4 (* __restrict__ wlds4)[256] = (uint4 (*)[256])smem;                 // [39][256]
    unsigned int (* __restrict__ hpk)[128] = (unsigned int (*)[128])(smem + 39 * 256 * 16);

    const int b   = blockIdx.x;
    const int tid = threadIdx.x;

    auto packq = [&](int row, int q) -> uint4 {   // 8 f32 -> 4 packed f16x2
        const f4* p = (const f4*)(whh + (size_t)row * 256 + q * 8);
        f4 v0 = p[0], v1 = p[1];
        uint4 u;
        u.x = pk2(v0.x, v0.y); u.y = pk2(v0.z, v0.w);
        u.z = pk2(v1.x, v1.y); u.w = pk2(v1.z, v1.w);
        return u;
    };
    auto pack16 = [&](int row, int q0) -> uv16 {
        uint4 a = packq(row, q0), c = packq(row, q0 + 1), d = packq(row, q0 + 2), e = packq(row, q0 + 3);
        uv16 W;
        W[0]=a.x; W[1]=a.y; W[2]=a.z; W[3]=a.w; W[4]=c.x; W[5]=c.y; W[6]=c.z; W[7]=c.w;
        W[8]=d.x; W[9]=d.y; W[10]=d.z; W[11]=d.w; W[12]=e.x; W[13]=e.y; W[14]=e.z; W[15]=e.w;
        return W;
    };

    // row_r fully in VGPR
    const uv16 wr0 = pack16(tid, 0),  wr1 = pack16(tid, 4),  wr2 = pack16(tid, 8),  wr3 = pack16(tid, 12),
               wr4 = pack16(tid, 16), wr5 = pack16(tid, 20), wr6 = pack16(tid, 24), wr7 = pack16(tid, 28);
    // row_z quads 0..24 in VGPR
    const int zr = 256 + tid;
    const uv16 wz0 = pack16(zr, 0),  wz1 = pack16(zr, 4),  wz2 = pack16(zr, 8),
               wz3 = pack16(zr, 12), wz4 = pack16(zr, 16), wz5 = pack16(zr, 20);
    const uint4 wz6 = packq(zr, 24);
    // row_z quads 25..31 -> wlds4[0..6][tid]; row_n quads 0..31 -> wlds4[7..38][tid]
    #pragma unroll
    for (int j = 0; j < 7; ++j) wlds4[j][tid] = packq(zr, 25 + j);
    #pragma unroll
    for (int q = 0; q < 32; ++q) wlds4[7 + q][tid] = packq(512 + tid, q);

    const float b_n = bhh[512 + tid];

    if (tid < 128) { hpk[0][tid] = 0u; hpk[1][tid] = 0u; }

    const _Float16* gb = gi + (size_t)b * TT * G3 + tid;
    float c_r = (float)gb[0];
    float c_z = (float)gb[256];
    float c_n = (float)gb[512];
    float hcur = 0.f;
    __syncthreads();

    for (int t = 0; t < TT; ++t) {
        // prefetch next step's gi (consumed after the ~1000cy dot phase)
        float p_r = 0.f, p_z = 0.f, p_n = 0.f;
        if (t + 1 < TT) {
            const _Float16* g2 = gb + (size_t)(t + 1) * G3;
            p_r = (float)g2[0];
            p_z = (float)g2[256];
            p_n = (float)g2[512];
        }

        const uint4* hb = (const uint4*)hpk[t & 1];
        float s0 = 0.f, s1 = 0.f, s2 = 0.f;

        #define QV(q, WR, WZ)                                            \
        {   uint4 hq = hb[q];                                            \
            s0 = dotq16<(q) & 3>(WR, hq, s0);                            \
            s1 = dotq16<(q) & 3>(WZ, hq, s1);                            \
            s2 = dotq4(wlds4[7 + (q)][tid], hq, s2); }
        #define QT(q)                                                    \
        {   uint4 hq = hb[q];                                            \
            s0 = dotq16<(q) & 3>(wr6, hq, s0);                           \
            s1 = dotq4(wz6, hq, s1);                                     \
            s2 = dotq4(wlds4[7 + (q)][tid], hq, s2); }
        #define QL(q, WR)                                                \
        {   uint4 hq = hb[q];                                            \
            s0 = dotq16<(q) & 3>(WR, hq, s0);                            \
            s1 = dotq4(wlds4[(q) - 25][tid], hq, s1);                    \
            s2 = dotq4(wlds4[7 + (q)][tid], hq, s2); }

        QV(0, wr0, wz0)  QV(1, wr0, wz0)  QV(2, wr0, wz0)  QV(3, wr0, wz0)
        QV(4, wr1, wz1)  QV(5, wr1, wz1)  QV(6, wr1, wz1)  QV(7, wr1, wz1)
        QV(8, wr2, wz2)  QV(9, wr2, wz2)  QV(10, wr2, wz2) QV(11, wr2, wz2)
        QV(12, wr3, wz3) QV(13, wr3, wz3) QV(14, wr3, wz3) QV(15, wr3, wz3)
        QV(16, wr4, wz4) QV(17, wr4, wz4) QV(18, wr4, wz4) QV(19, wr4, wz4)
        QV(20, wr5, wz5) QV(21, wr5, wz5) QV(22, wr5, wz5) QV(23, wr5, wz5)
        QT(24)
        QL(25, wr6) QL(26, wr6) QL(27, wr6)
        QL(28, wr7) QL(29, wr7) QL(30, wr7) QL(31, wr7)
        #undef QV
        #undef QT
        #undef QL

        // gate math: c_r/c_z carry bih+bhh; c_n carries bih only (b_hn r-gated)
        const float r = __builtin_amdgcn_rcpf(1.f + __expf(-(c_r + s0)));
        const float z = __builtin_amdgcn_rcpf(1.f + __expf(-(c_z + s1)));
        const float xn = c_n + r * (s2 + b_n);
        const float th = 1.f - 2.f * __builtin_amdgcn_rcpf(__expf(2.f * xn) + 1.f);
        hcur = (1.f - z) * th + z * hcur;

        ((_Float16*)hpk[(t + 1) & 1])[tid] = (_Float16)hcur;
        c_r = p_r; c_z = p_z; c_n = p_n;
        __syncthreads();
    }

    out[(size_t)b * HH + tid] = hcur;
}

// ---------------------------------------------------------------------------
extern "C" void kernel_launch(void* const* d_in, const int* in_sizes, int n_in,
                              void* d_out, int out_size, void* d_ws, size_t ws_size,
                              hipStream_t stream) {
    const float* x   = (const float*)d_in[0];
    const float* wih = (const float*)d_in[1];
    const float* whh = (const float*)d_in[2];
    const float* bih = (const float*)d_in[3];
    const float* bhh = (const float*)d_in[4];
    float* out = (float*)d_out;

    // workspace: [0, 384KB) W_ih fp16 ; [512KB, 512KB+192MB) gi fp16
    _Float16* wih_h = (_Float16*)d_ws;
    _Float16* gi    = (_Float16*)((char*)d_ws + 512 * 1024);

    const int lds_bytes = 39 * 256 * 16 + 2 * 128 * 4;  // 160768
    hipFuncSetAttribute((const void*)gru_scan,
                        hipFuncAttributeMaxDynamicSharedMemorySize, lds_bytes);

    cast_wih<<<768, 256, 0, stream>>>(wih, wih_h, G3 * II);
    gi_gemm<<<6144, 256, 0, stream>>>(x, wih_h, bih, bhh, gi);
    gru_scan<<<BB, 256, lds_bytes, stream>>>(gi, whh, bhh, out);
}